// Round 2
// baseline (2473.689 us; speedup 1.0000x reference)
//
#include <hip/hip_runtime.h>
#include <math.h>

#define H   39
#define G4  156   // 4*H
#define TL  2048  // T
#define BB  512   // B

// Block: 320 threads (5 waves), one (batch, direction) per block.
// Lane mapping inside wave w (covers h-indices n in [8w, 8w+8)):
//   lane = n_local*8 + g*2 + p   (n_local 0..7, gate g 0..3 = i,f,g,o, k-half p)
// All 4 gate rows of an h-index n live in ONE 8-lane group -> gates are
// exchanged with intra-wave shuffles (no LDS, no barrier). Every lane of the
// group redundantly updates (c,h) for its n. Only h itself crosses waves,
// via ping-pong LDS buffers + ONE __syncthreads per timestep (was 2).
__global__ __launch_bounds__(320, 5)
void lstm_bidir_kernel(const float* __restrict__ x,
                       const float* __restrict__ W_ih_f, const float* __restrict__ W_hh_f,
                       const float* __restrict__ b_ih_f, const float* __restrict__ b_hh_f,
                       const float* __restrict__ W_ih_b, const float* __restrict__ W_hh_b,
                       const float* __restrict__ b_ih_b, const float* __restrict__ b_hh_b,
                       float* __restrict__ out)
{
    const int blk = blockIdx.x;        // 0..1023
    const int b   = blk >> 1;          // batch element
    const int dir = blk & 1;           // 0 = forward, 1 = backward
    const int tid = threadIdx.x;
    const int wav = tid >> 6;          // wave 0..4
    const int lan = tid & 63;
    const int nl  = lan >> 3;          // n_local 0..7
    const int g   = (lan >> 1) & 3;    // gate 0..3 (PyTorch order i,f,g,o)
    const int p   = lan & 1;           // k-half
    const int n   = (wav << 3) + nl;   // h index 0..39 (n==39 is padding)
    const bool nv = (n < H);
    const int j   = g * H + n;         // gate row in W (valid when nv)

    const float* __restrict__ W_ih = dir ? W_ih_b : W_ih_f;
    const float* __restrict__ W_hh = dir ? W_hh_b : W_hh_f;
    const float* __restrict__ b_ih = dir ? b_ih_b : b_ih_f;
    const float* __restrict__ b_hh = dir ? b_hh_b : b_hh_f;

    // ping-pong x/h buffers; index 39 stays 0 forever (read by k=39 pad chunk)
    __shared__ __align__(16) float xb[2][40];
    __shared__ __align__(16) float hb[2][40];

    // ---- per-lane weight chunks in registers: k in {8m+4p .. 8m+4p+3} ----
    float4 wih[5], whh[5];
    float bias = 0.0f;
    #pragma unroll
    for (int m = 0; m < 5; ++m) {
        const int k0 = 8 * m + 4 * p;
        float a[4], hh[4];
        #pragma unroll
        for (int e = 0; e < 4; ++e) {
            const int k = k0 + e;
            const bool kv = nv && (k < H);
            a[e]  = kv ? W_ih[j * H + k] : 0.0f;
            hh[e] = kv ? W_hh[j * H + k] : 0.0f;
        }
        wih[m] = make_float4(a[0], a[1], a[2], a[3]);
        whh[m] = make_float4(hh[0], hh[1], hh[2], hh[3]);
    }
    if (nv) bias = b_ih[j] + b_hh[j];

    // branchless activation: gate 2 uses tanh(x) = 2*sigmoid(2x) - 1
    const float amul = (g == 2) ? 2.0f : 1.0f;
    const float aoff = (g == 2) ? -1.0f : 0.0f;

    const float* __restrict__ xrow = x + (size_t)b * (TL * H);
    float* __restrict__ orow = out + (size_t)b * (TL * 2 * H) + dir * H;

    if (tid < 40) {
        hb[0][tid] = 0.0f;
        hb[1][tid] = 0.0f;
        xb[1][tid] = 0.0f;
        const int t0 = dir ? (TL - 1) : 0;
        xb[0][tid] = (tid < H) ? xrow[(size_t)t0 * H + tid] : 0.0f;
    }
    __syncthreads();

    float c = 0.0f;                    // cell state (identical copies in the 8-lane group)
    const bool hwr = (g == 0) && (p == 0) && nv;   // writes h to LDS
    const bool xld = (g == 1) && (p == 0) && nv;   // loads + writes next x
    const bool ost = (g == 2) && (p == 0) && nv;   // stores output

    for (int s = 0; s < TL; ++s) {
        const int cur = s & 1, nxt = cur ^ 1;

        // prefetch next timestep's x (consumed at bottom of loop)
        float xnext = 0.0f;
        if (xld && (s + 1) < TL) {
            const int tn = dir ? (TL - 2 - s) : (s + 1);
            xnext = xrow[(size_t)tn * H + n];
        }

        const float4* xb4 = (const float4*)xb[cur];
        const float4* hb4 = (const float4*)hb[cur];
        float4 acc = make_float4(0.0f, 0.0f, 0.0f, 0.0f);
        #pragma unroll
        for (int m = 0; m < 5; ++m) {
            const int ci = 2 * m + p;
            const float4 xv = xb4[ci];
            const float4 hv = hb4[ci];
            acc.x = fmaf(wih[m].x, xv.x, fmaf(whh[m].x, hv.x, acc.x));
            acc.y = fmaf(wih[m].y, xv.y, fmaf(whh[m].y, hv.y, acc.y));
            acc.z = fmaf(wih[m].z, xv.z, fmaf(whh[m].z, hv.z, acc.z));
            acc.w = fmaf(wih[m].w, xv.w, fmaf(whh[m].w, hv.w, acc.w));
        }
        float psum = (acc.x + acc.y) + (acc.z + acc.w);
        const float tot  = psum + __shfl_xor(psum, 1) + bias;
        const float targ = amul * tot;
        const float e    = __expf(-targ);
        const float act  = fmaf(amul, __builtin_amdgcn_rcpf(1.0f + e), aoff);

        // gather the 4 gates of this n from even (p==0) lanes of the group
        const int base = lan & ~7;
        const float ig = __shfl(act, base + 0);
        const float fg = __shfl(act, base + 2);
        const float gg = __shfl(act, base + 4);
        const float og = __shfl(act, base + 6);

        c = fmaf(fg, c, ig * gg);
        const float e2 = __expf(-2.0f * c);
        const float th = fmaf(2.0f, __builtin_amdgcn_rcpf(1.0f + e2), -1.0f);
        const float h  = og * th;

        if (hwr) hb[nxt][n] = h;       // next step's h
        if (xld) xb[nxt][n] = xnext;   // next step's x (0 on last step, unused)
        if (ost) orow[(size_t)s * (2 * H) + n] = h;

        __syncthreads();               // single barrier: publishes hb/xb[nxt]
    }
}

extern "C" void kernel_launch(void* const* d_in, const int* in_sizes, int n_in,
                              void* d_out, int out_size, void* d_ws, size_t ws_size,
                              hipStream_t stream) {
    const float* x      = (const float*)d_in[0];
    const float* W_ih_f = (const float*)d_in[1];
    const float* W_hh_f = (const float*)d_in[2];
    const float* b_ih_f = (const float*)d_in[3];
    const float* b_hh_f = (const float*)d_in[4];
    const float* W_ih_b = (const float*)d_in[5];
    const float* W_hh_b = (const float*)d_in[6];
    const float* b_ih_b = (const float*)d_in[7];
    const float* b_hh_b = (const float*)d_in[8];
    float* out = (float*)d_out;

    dim3 grid(BB * 2);   // one block per (batch, direction)
    dim3 block(320);     // 5 waves; lane = (n_local, gate, k-half)
    lstm_bidir_kernel<<<grid, block, 0, stream>>>(
        x, W_ih_f, W_hh_f, b_ih_f, b_hh_f,
        W_ih_b, W_hh_b, b_ih_b, b_hh_b, out);
}